// Round 1
// baseline (457.164 us; speedup 1.0000x reference)
//
#include <hip/hip_runtime.h>
#include <math.h>

#define BB 4
#define CC 128
#define BT 32
#define NBOX 4
#define HH 256
#define WW 256
#define HW (HH*WW)
#define SP 257
#define SPLANE (SP*SP)

// ---------------- Kernel A: 1x1 conv (128->32) + BN1 ----------------
__global__ __launch_bounds__(256) void conv_bn1(
        const float* __restrict__ x, const float* __restrict__ w1,
        const float* __restrict__ g1, const float* __restrict__ b1,
        const float* __restrict__ m1, const float* __restrict__ v1,
        float* __restrict__ h) {
    int pix = blockIdx.x * 256 + threadIdx.x;   // over B*HW
    int b  = pix >> 16;
    int ij = pix & 65535;
    const float* xb = x + b * (CC * HW) + ij;
    float acc[BT];
    #pragma unroll
    for (int k = 0; k < BT; ++k) acc[k] = 0.f;
    #pragma unroll 4
    for (int c = 0; c < CC; ++c) {
        float xv = xb[c * HW];
        #pragma unroll
        for (int k = 0; k < BT; ++k)
            acc[k] = fmaf(xv, w1[k * CC + c], acc[k]);
    }
    float* hb = h + b * (BT * HW) + ij;
    #pragma unroll
    for (int k = 0; k < BT; ++k) {
        float inv = g1[k] / sqrtf(v1[k] + 1e-5f);
        float add = b1[k] - m1[k] * inv;
        hb[k * HW] = acc[k] * inv + add;
    }
}

// ---------------- Kernel B1: inclusive row scan (along W), in place ----------------
__global__ __launch_bounds__(256) void row_scan(float* __restrict__ t) {
    __shared__ float buf[256];
    int base = blockIdx.x * WW;          // one block per (b,k,i) row
    int tid = threadIdx.x;
    buf[tid] = t[base + tid];
    __syncthreads();
    #pragma unroll
    for (int off = 1; off < 256; off <<= 1) {
        float prev = (tid >= off) ? buf[tid - off] : 0.f;
        __syncthreads();
        buf[tid] += prev;
        __syncthreads();
    }
    t[base + tid] = buf[tid];
}

// ---------------- Kernel B2: column scan -> zero-padded integral image S ----------------
// grid = B*BT*4 blocks of 64 threads; each block owns 64 columns of one plane.
__global__ __launch_bounds__(64) void col_scan(const float* __restrict__ t,
                                               float* __restrict__ s) {
    int plane = blockIdx.x >> 2;
    int cb = (blockIdx.x & 3) * 64;
    int j = cb + threadIdx.x;
    const float* tp = t + plane * HW;
    float* sp = s + plane * SPLANE;
    // zero padding (workspace is poisoned every launch)
    sp[j + 1] = 0.f;              // row 0, cols 1..256
    sp[(j + 1) * SP] = 0.f;       // col 0, rows 1..256
    if (j == 0) sp[0] = 0.f;      // corner
    float run = 0.f;
    #pragma unroll 4
    for (int i = 0; i < HH; ++i) {
        run += tp[i * WW + j];
        sp[(i + 1) * SP + (j + 1)] = run;
    }
}

// ---------------- Kernel C: box bilinear sample + BN2 + relu + residual + relu ----------------
// grid = B*BT*NBOX*H blocks; thread = output column j.
__global__ __launch_bounds__(256) void box_sample(
        const float* __restrict__ s, const float* __restrict__ x,
        const float* __restrict__ xmin, const float* __restrict__ xmax,
        const float* __restrict__ ymin, const float* __restrict__ ymax,
        const float* __restrict__ g2, const float* __restrict__ b2,
        const float* __restrict__ m2, const float* __restrict__ v2,
        float* __restrict__ out) {
    int bid = blockIdx.x;
    int i = bid & 255;
    int n = (bid >> 8) & 3;
    int k = (bid >> 10) & 31;
    int b = bid >> 15;
    int j = threadIdx.x;
    int kn = k * NBOX + n;                  // box index == output channel
    const float* sp = s + (b * BT + k) * SPLANE;

    float xmn = xmin[kn], xmx = xmax[kn], ymn = ymin[kn], ymx = ymax[kn];

    // vertical coords (rows of S)
    float u_hi = fminf(fmaxf((float)i + xmx, 0.f), 256.f);
    float u_lo = fminf(fmaxf((float)i + xmn, 0.f), 256.f);
    int i1 = (int)fminf(floorf(u_hi), 255.f);
    int i0 = (int)fminf(floorf(u_lo), 255.f);
    float wu1 = u_hi - (float)i1;
    float wu0 = u_lo - (float)i0;
    // horizontal coords (cols of S)
    float v_hi = fminf(fmaxf((float)j + ymx, 0.f), 256.f);
    float v_lo = fminf(fmaxf((float)j + ymn, 0.f), 256.f);
    int j1 = (int)fminf(floorf(v_hi), 255.f);
    int j0 = (int)fminf(floorf(v_lo), 255.f);
    float wv1 = v_hi - (float)j1;
    float wv0 = v_lo - (float)j0;

    const float* rA = sp + i1 * SP;   // hi rows
    const float* rB = rA + SP;
    const float* rC = sp + i0 * SP;   // lo rows
    const float* rD = rC + SP;

    float Rh1 = rA[j1]   * (1.f - wu1) + rB[j1]   * wu1;
    float Rh2 = rA[j1+1] * (1.f - wu1) + rB[j1+1] * wu1;
    float F11 = Rh1 * (1.f - wv1) + Rh2 * wv1;
    float Rh3 = rA[j0]   * (1.f - wu1) + rB[j0]   * wu1;
    float Rh4 = rA[j0+1] * (1.f - wu1) + rB[j0+1] * wu1;
    float F10 = Rh3 * (1.f - wv0) + Rh4 * wv0;
    float Rl1 = rC[j1]   * (1.f - wu0) + rD[j1]   * wu0;
    float Rl2 = rC[j1+1] * (1.f - wu0) + rD[j1+1] * wu0;
    float F01 = Rl1 * (1.f - wv1) + Rl2 * wv1;
    float Rl3 = rC[j0]   * (1.f - wu0) + rD[j0]   * wu0;
    float Rl4 = rC[j0+1] * (1.f - wu0) + rD[j0+1] * wu0;
    float F00 = Rl3 * (1.f - wv0) + Rl4 * wv0;

    float area = (xmx - xmn) * (ymx - ymn);
    float val = (F11 - F10 - F01 + F00) / area;
    float inv = g2[kn] / sqrtf(v2[kn] + 1e-3f);
    float add = b2[kn] - m2[kn] * inv;
    val = val * inv + add;
    val = fmaxf(val, 0.f);                        // relu(bn2)
    int oidx = ((b * CC + kn) * HH + i) * WW + j;
    out[oidx] = fmaxf(x[oidx] + val, 0.f);        // relu(x + h)
}

extern "C" void kernel_launch(void* const* d_in, const int* in_sizes, int n_in,
                              void* d_out, int out_size, void* d_ws, size_t ws_size,
                              hipStream_t stream) {
    const float* x    = (const float*)d_in[0];
    const float* w1   = (const float*)d_in[1];
    const float* g1   = (const float*)d_in[2];
    const float* b1   = (const float*)d_in[3];
    const float* m1   = (const float*)d_in[4];
    const float* v1   = (const float*)d_in[5];
    const float* xmin = (const float*)d_in[6];
    const float* xmax = (const float*)d_in[7];
    const float* ymin = (const float*)d_in[8];
    const float* ymax = (const float*)d_in[9];
    const float* g2   = (const float*)d_in[10];
    const float* b2   = (const float*)d_in[11];
    const float* m2   = (const float*)d_in[12];
    const float* v2   = (const float*)d_in[13];
    float* out = (float*)d_out;

    float* h = (float*)d_ws;                        // B*BT*HW floats (33.5 MB)
    float* S = h + (size_t)BB * BT * HW;            // B*BT*SPLANE floats (33.8 MB)

    conv_bn1 <<<(BB * HW) / 256, 256, 0, stream>>>(x, w1, g1, b1, m1, v1, h);
    row_scan <<<BB * BT * HH, 256, 0, stream>>>(h);
    col_scan <<<BB * BT * 4, 64, 0, stream>>>(h, S);
    box_sample<<<BB * BT * NBOX * HH, 256, 0, stream>>>(S, x, xmin, xmax, ymin, ymax,
                                                        g2, b2, m2, v2, out);
}

// Round 2
// 390.510 us; speedup vs baseline: 1.1707x; 1.1707x over previous
//
#include <hip/hip_runtime.h>
#include <math.h>

#define BB 4
#define CC 128
#define BT 32
#define NBOX 4
#define HH 256
#define WW 256
#define HW (HH*WW)
#define SP 257
#define SPLANE (SP*SP)
#define NPLANE (BB*BT)          // 128 integral-image planes
#define CHUNK 32                // rows per column-scan chunk
#define NCHUNK (HH/CHUNK)       // 8

// ---------------- Kernel A: 1x1 conv (128->32) + BN1 ----------------
__global__ __launch_bounds__(256) void conv_bn1(
        const float* __restrict__ x, const float* __restrict__ w1,
        const float* __restrict__ g1, const float* __restrict__ b1,
        const float* __restrict__ m1, const float* __restrict__ v1,
        float* __restrict__ h) {
    int pix = blockIdx.x * 256 + threadIdx.x;   // over B*HW
    int b  = pix >> 16;
    int ij = pix & 65535;
    const float* xb = x + b * (CC * HW) + ij;
    float acc[BT];
    #pragma unroll
    for (int k = 0; k < BT; ++k) acc[k] = 0.f;
    #pragma unroll 4
    for (int c = 0; c < CC; ++c) {
        float xv = xb[c * HW];
        #pragma unroll
        for (int k = 0; k < BT; ++k)
            acc[k] = fmaf(xv, w1[k * CC + c], acc[k]);
    }
    float* hb = h + b * (BT * HW) + ij;
    #pragma unroll
    for (int k = 0; k < BT; ++k) {
        float inv = g1[k] * __frsqrt_rn(v1[k] + 1e-5f);
        float add = b1[k] - m1[k] * inv;
        hb[k * HW] = acc[k] * inv + add;
    }
}

// ---------------- Kernel B1: inclusive row scan (along W), in place ----------------
// One wave per row; lane owns 4 contiguous elements (float4). No barriers.
__global__ __launch_bounds__(256) void row_scan(float* __restrict__ t) {
    int wave = threadIdx.x >> 6;
    int lane = threadIdx.x & 63;
    int row = blockIdx.x * 4 + wave;            // over B*BT*H rows
    float4* rp = (float4*)(t + (size_t)row * WW) + lane;
    float4 v = *rp;
    v.y += v.x; v.z += v.y; v.w += v.z;
    float tot = v.w;
    float sum = tot;
    #pragma unroll
    for (int off = 1; off < 64; off <<= 1) {
        float o = __shfl_up(sum, off, 64);
        if (lane >= off) sum += o;
    }
    float excl = sum - tot;                     // exclusive prefix of lane totals
    v.x += excl; v.y += excl; v.z += excl; v.w += excl;
    *rp = v;
}

// ---------------- Kernel B2a: per-chunk column partial sums ----------------
// grid = NPLANE*NCHUNK blocks of 256; thread = column j.
__global__ __launch_bounds__(256) void col_partial(const float* __restrict__ t,
                                                   float* __restrict__ T) {
    int plane = blockIdx.x >> 3;
    int chunk = blockIdx.x & 7;
    int j = threadIdx.x;
    const float* tp = t + (size_t)plane * HW + chunk * CHUNK * WW + j;
    float s = 0.f;
    #pragma unroll 8
    for (int r = 0; r < CHUNK; ++r) s += tp[r * WW];
    T[blockIdx.x * 256 + j] = s;
}

// ---------------- Kernel B2b: column scan with chunk offsets -> padded S ----------------
__global__ __launch_bounds__(256) void col_final(const float* __restrict__ t,
                                                 const float* __restrict__ T,
                                                 float* __restrict__ s) {
    int plane = blockIdx.x >> 3;
    int chunk = blockIdx.x & 7;
    int j = threadIdx.x;
    float off = 0.f;
    for (int c = 0; c < chunk; ++c) off += T[(plane * 8 + c) * 256 + j];
    const float* tp = t + (size_t)plane * HW + chunk * CHUNK * WW + j;
    float* sp = s + (size_t)plane * SPLANE;
    if (chunk == 0) {                    // top padding row
        sp[j + 1] = 0.f;
        if (j == 0) sp[0] = 0.f;
    }
    float run = off;
    int rowbase = chunk * CHUNK;
    #pragma unroll 4
    for (int r = 0; r < CHUNK; ++r) {
        run += tp[r * WW];
        sp[(size_t)(rowbase + r + 1) * SP + j + 1] = run;
        if (j == 0) sp[(size_t)(rowbase + r + 1) * SP] = 0.f;   // left padding col
    }
}

// ---------------- Kernel C: box sample via shared D-row + BN2 + relus ----------------
// grid = B*BT*NBOX*H blocks; thread = output column j.
__global__ __launch_bounds__(256) void box_sample(
        const float* __restrict__ s, const float* __restrict__ x,
        const float* __restrict__ xmin, const float* __restrict__ xmax,
        const float* __restrict__ ymin, const float* __restrict__ ymax,
        const float* __restrict__ g2, const float* __restrict__ b2,
        const float* __restrict__ m2, const float* __restrict__ v2,
        float* __restrict__ out) {
    __shared__ float D[SP];
    int bid = blockIdx.x;
    int i = bid & 255;
    int n = (bid >> 8) & 3;
    int k = (bid >> 10) & 31;
    int b = bid >> 15;
    int j = threadIdx.x;
    int kn = k * NBOX + n;
    const float* sp = s + (size_t)(b * BT + k) * SPLANE;

    float xmn = xmin[kn], xmx = xmax[kn], ymn = ymin[kn], ymx = ymax[kn];

    // row (vertical) interpolation setup — wave-uniform
    float u_hi = fminf(fmaxf((float)i + xmx, 0.f), 256.f);
    float u_lo = fminf(fmaxf((float)i + xmn, 0.f), 256.f);
    int i1 = (int)fminf(floorf(u_hi), 255.f);
    int i0 = (int)fminf(floorf(u_lo), 255.f);
    float wu1 = u_hi - (float)i1;
    float wu0 = u_lo - (float)i0;

    const float* rA = sp + (size_t)i1 * SP;
    const float* rB = rA + SP;
    const float* rC = sp + (size_t)i0 * SP;
    const float* rD = rC + SP;

    // D[v] = rowHi(v) - rowLo(v), cooperatively over 257 columns
    D[j] = rA[j] * (1.f - wu1) + rB[j] * wu1 - rC[j] * (1.f - wu0) - rD[j] * wu0;
    if (j == 0)
        D[256] = rA[256] * (1.f - wu1) + rB[256] * wu1
               - rC[256] * (1.f - wu0) - rD[256] * wu0;
    __syncthreads();

    // column (horizontal) interpolation — per-lane
    float v_hi = fminf(fmaxf((float)j + ymx, 0.f), 256.f);
    float v_lo = fminf(fmaxf((float)j + ymn, 0.f), 256.f);
    int j1 = (int)fminf(floorf(v_hi), 255.f);
    int j0 = (int)fminf(floorf(v_lo), 255.f);
    float wv1 = v_hi - (float)j1;
    float wv0 = v_lo - (float)j0;

    float hi = D[j1] * (1.f - wv1) + D[j1 + 1] * wv1;
    float lo = D[j0] * (1.f - wv0) + D[j0 + 1] * wv0;

    float inv = g2[kn] * __frsqrt_rn(v2[kn] + 1e-3f);
    float scale = inv * __frcp_rn((xmx - xmn) * (ymx - ymn));
    float add = b2[kn] - m2[kn] * inv;
    float val = (hi - lo) * scale + add;
    val = fmaxf(val, 0.f);                        // relu(bn2)
    size_t oidx = ((size_t)(b * CC + kn) * HH + i) * WW + j;
    out[oidx] = fmaxf(x[oidx] + val, 0.f);        // relu(x + h)
}

extern "C" void kernel_launch(void* const* d_in, const int* in_sizes, int n_in,
                              void* d_out, int out_size, void* d_ws, size_t ws_size,
                              hipStream_t stream) {
    const float* x    = (const float*)d_in[0];
    const float* w1   = (const float*)d_in[1];
    const float* g1   = (const float*)d_in[2];
    const float* b1   = (const float*)d_in[3];
    const float* m1   = (const float*)d_in[4];
    const float* v1   = (const float*)d_in[5];
    const float* xmin = (const float*)d_in[6];
    const float* xmax = (const float*)d_in[7];
    const float* ymin = (const float*)d_in[8];
    const float* ymax = (const float*)d_in[9];
    const float* g2   = (const float*)d_in[10];
    const float* b2   = (const float*)d_in[11];
    const float* m2   = (const float*)d_in[12];
    const float* v2   = (const float*)d_in[13];
    float* out = (float*)d_out;

    float* h = (float*)d_ws;                        // B*BT*HW floats (33.5 MB)
    float* S = h + (size_t)BB * BT * HW;            // NPLANE*SPLANE floats (33.8 MB)
    float* T = S + (size_t)NPLANE * SPLANE;         // NPLANE*NCHUNK*256 floats (1 MB)

    conv_bn1   <<<(BB * HW) / 256, 256, 0, stream>>>(x, w1, g1, b1, m1, v1, h);
    row_scan   <<<BB * BT * HH / 4, 256, 0, stream>>>(h);
    col_partial<<<NPLANE * NCHUNK, 256, 0, stream>>>(h, T);
    col_final  <<<NPLANE * NCHUNK, 256, 0, stream>>>(h, T, S);
    box_sample <<<BB * BT * NBOX * HH, 256, 0, stream>>>(S, x, xmin, xmax, ymin, ymax,
                                                         g2, b2, m2, v2, out);
}